// Round 8
// baseline (589.185 us; speedup 1.0000x reference)
//
#include <hip/hip_runtime.h>
#include <hip/hip_bf16.h>

#define B_   2048
#define L_   200
#define DM_  512
#define HID_ 256
#define V_   40000
#define NPAD 40064          // 313 * 128
#define LN_EPS 1e-5f

typedef short bf16x8 __attribute__((ext_vector_type(8)));
typedef float f32x4  __attribute__((ext_vector_type(4)));

#define GLOAD_LDS16(g, l)                                                     \
    __builtin_amdgcn_global_load_lds(                                         \
        (const __attribute__((address_space(1))) void*)(g),                   \
        (__attribute__((address_space(3))) void*)(l), 16, 0, 0)

#define BM 128
#define BN 128

// R6 XCD-grouped block->tile mapping, shared by gemm variants + store probe
__device__ inline void tile_map(int g, int& rt, int& ct) {
    const int G = g >> 7, ii = g & 127;
    if (G < 39) { ct = G * 8 + (ii & 7); rt = ii >> 3; }
    else        { ct = 312;              rt = ii & 15; }
}

// ---------------------------------------------------------------------------
// Kernel 1: W2 transpose+cvt (unchanged)
// ---------------------------------------------------------------------------
__global__ __launch_bounds__(256) void transpose_w2(const float* __restrict__ W2,
                                                    __hip_bfloat16* __restrict__ WT) {
    __shared__ float tile[64][65];
    const int n0 = blockIdx.x * 64;
    const int k0 = blockIdx.y * 64;
    const int tid = threadIdx.x;

    const int c = tid & 63, r4 = tid >> 6;
#pragma unroll
    for (int p = 0; p < 16; ++p) {
        int r = p * 4 + r4;
        int n = n0 + c;
        tile[r][c] = (n < V_) ? W2[(size_t)(k0 + r) * V_ + n] : 0.f;
    }
    __syncthreads();

    const int nl = tid >> 3;
    const int kb = (tid & 7) * 8;
#pragma unroll
    for (int p = 0; p < 2; ++p) {
        int n = p * 32 + nl;
        bf16x8 v;
#pragma unroll
        for (int j = 0; j < 8; ++j) {
            __hip_bfloat16 h = __float2bfloat16(tile[kb + j][n]);
            v[j] = *(short*)&h;
        }
        *(bf16x8*)(WT + (size_t)(n0 + n) * HID_ + k0 + kb) = v;
    }
}

// ---------------------------------------------------------------------------
// Kernel 2: head (unchanged)
// ---------------------------------------------------------------------------
__global__ __launch_bounds__(512) void head_kernel(const float* __restrict__ hidden,
                                                   const float* __restrict__ W1,
                                                   const float* __restrict__ b1,
                                                   const float* __restrict__ gamma,
                                                   const float* __restrict__ beta,
                                                   __hip_bfloat16* __restrict__ hout) {
    __shared__ float hid[8][DM_];
    __shared__ float part[8][HID_];
    __shared__ float red[2][8][4];
    const int r0 = blockIdx.x * 8;
    const int tid = threadIdx.x;
    const int col = tid & 255, half = tid >> 8;

    {
        const float4* src = (const float4*)(hidden + (size_t)r0 * DM_);
        float4* dst = (float4*)(&hid[0][0]);
        for (int i = tid; i < 8 * DM_ / 4; i += 512) dst[i] = src[i];
    }
    __syncthreads();

    float acc[8] = {0.f, 0.f, 0.f, 0.f, 0.f, 0.f, 0.f, 0.f};
    const int kbeg = half * (DM_ / 2);
#pragma unroll 8
    for (int k = kbeg; k < kbeg + DM_ / 2; ++k) {
        float w = W1[(size_t)k * HID_ + col];
#pragma unroll
        for (int r = 0; r < 8; ++r) acc[r] = fmaf(hid[r][k], w, acc[r]);
    }

    if (half == 1) {
#pragma unroll
        for (int r = 0; r < 8; ++r) part[r][col] = acc[r];
    }
    __syncthreads();
    if (half == 0) {
        const float b1v = b1[col], gv = gamma[col], bev = beta[col];
        const int lane = col & 63, wv = col >> 6;
        float v[8];
#pragma unroll
        for (int r = 0; r < 8; ++r) {
            v[r] = acc[r] + part[r][col] + b1v;
            float s = v[r], q = v[r] * v[r];
#pragma unroll
            for (int off = 1; off < 64; off <<= 1) {
                s += __shfl_xor(s, off);
                q += __shfl_xor(q, off);
            }
            if (lane == 0) { red[0][r][wv] = s; red[1][r][wv] = q; }
        }
        __syncthreads();
#pragma unroll
        for (int r = 0; r < 8; ++r) {
            float s  = red[0][r][0] + red[0][r][1] + red[0][r][2] + red[0][r][3];
            float q  = red[1][r][0] + red[1][r][1] + red[1][r][2] + red[1][r][3];
            float mu = s * (1.f / HID_);
            float var = q * (1.f / HID_) - mu * mu;
            float hn = (v[r] - mu) * rsqrtf(var + LN_EPS) * gv + bev;
            float g  = 0.5f * hn * (1.f + erff(hn * 0.70710678118654752f));
            hout[(size_t)(r0 + r) * HID_ + col] = __float2bfloat16(g);
        }
    }
}

// ---------------------------------------------------------------------------
// Kernel 3: GEMM — R6 body, templated: EPI=1 real stores, EPI=0 asm sink.
// ---------------------------------------------------------------------------
template <int EPI>
__global__ __launch_bounds__(256, 1) void gemm_kernel(const __hip_bfloat16* __restrict__ hA,
                                                      const __hip_bfloat16* __restrict__ BT,
                                                      const float* __restrict__ b2,
                                                      const float* __restrict__ lsp,
                                                      float* __restrict__ out) {
    __shared__ __hip_bfloat16 As[BM * HID_];   // 64 KB
    __shared__ __hip_bfloat16 Bs[BN * HID_];   // 64 KB

    int rt, ct;
    tile_map(blockIdx.x, rt, ct);
    const int r0 = rt * BM, c0 = ct * BN;

    const int tid = threadIdx.x;
    const int lane = tid & 63;
    const int wv = tid >> 6;
    const int wr = (wv >> 1) * 64;
    const int wc = (wv & 1) * 64;
    const float ls = lsp[0];

    {
        const __hip_bfloat16* aB = hA + (size_t)r0 * HID_;
        const __hip_bfloat16* bB = BT + (size_t)c0 * HID_;
        const int cc = lane & 31;
        const int rhalf = lane >> 5;
#pragma unroll
        for (int i = 0; i < 16; ++i) {
            const int ch = wv * 16 + i;
            const int r = ch * 2 + rhalf;
            const int csrc = cc ^ (r & 7);
            GLOAD_LDS16(aB + (size_t)r * HID_ + csrc * 8, (char*)As + ch * 1024);
            GLOAD_LDS16(bB + (size_t)r * HID_ + csrc * 8, (char*)Bs + ch * 1024);
        }
    }
    __syncthreads();

    f32x4 acc[4][4];
#pragma unroll
    for (int m = 0; m < 4; ++m)
#pragma unroll
        for (int n = 0; n < 4; ++n) acc[m][n] = (f32x4){0.f, 0.f, 0.f, 0.f};

    const int rb = wr + (lane & 15);
    const int cb = wc + (lane & 15);
#pragma unroll
    for (int ks = 0; ks < HID_ / 32; ++ks) {
        const int kb = ks * 32 + ((lane >> 4) << 3);
        const int ke = kb ^ ((lane & 7) << 3);
        bf16x8 af[4], bf[4];
#pragma unroll
        for (int m = 0; m < 4; ++m)
            af[m] = *(const bf16x8*)(As + (size_t)(rb + m * 16) * HID_ + ke);
#pragma unroll
        for (int n = 0; n < 4; ++n)
            bf[n] = *(const bf16x8*)(Bs + (size_t)(cb + n * 16) * HID_ + ke);
#pragma unroll
        for (int m = 0; m < 4; ++m)
#pragma unroll
            for (int n = 0; n < 4; ++n)
                acc[m][n] = __builtin_amdgcn_mfma_f32_16x16x32_bf16(
                    bf[n], af[m], acc[m][n], 0, 0, 0);
    }

    if (EPI) {
        const int orow = r0 + wr + (lane & 15);
        const int ocol = c0 + wc + ((lane >> 4) << 2);
        f32x4 b2v[4];
#pragma unroll
        for (int n = 0; n < 4; ++n) {
            int col = ocol + n * 16;
            b2v[n] = (col < V_) ? *(const f32x4*)(b2 + col)
                                : (f32x4){0.f, 0.f, 0.f, 0.f};
        }
#pragma unroll
        for (int m = 0; m < 4; ++m) {
            float* orp = out + (size_t)(orow + m * 16) * V_;
#pragma unroll
            for (int n = 0; n < 4; ++n) {
                int col = ocol + n * 16;
                if (col < V_) {
                    f32x4 o = (acc[m][n] + b2v[n]) * ls;
                    __builtin_nontemporal_store(o, (f32x4*)(orp + col));
                }
            }
        }
    } else {
        // keep acc live without stores (rule #17)
#pragma unroll
        for (int m = 0; m < 4; ++m)
#pragma unroll
            for (int n = 0; n < 4; ++n)
                asm volatile("" :: "v"(acc[m][n][0]), "v"(acc[m][n][1]),
                                   "v"(acc[m][n][2]), "v"(acc[m][n][3]));
    }
}

// ---------------------------------------------------------------------------
// Store probe: exact R6 store pattern, constant data, no LDS/MFMA.
// ---------------------------------------------------------------------------
__global__ __launch_bounds__(256) void store_probe(const float* __restrict__ lsp,
                                                   float* __restrict__ out) {
    int rt, ct;
    tile_map(blockIdx.x, rt, ct);
    const int r0 = rt * BM, c0 = ct * BN;
    const int lane = threadIdx.x & 63;
    const int wv = threadIdx.x >> 6;
    const int wr = (wv >> 1) * 64;
    const int wc = (wv & 1) * 64;
    const float ls = lsp[0];
    f32x4 o = (f32x4){ls, ls, ls, ls};

    const int orow = r0 + wr + (lane & 15);
    const int ocol = c0 + wc + ((lane >> 4) << 2);
#pragma unroll
    for (int m = 0; m < 4; ++m) {
        float* orp = out + (size_t)(orow + m * 16) * V_;
#pragma unroll
        for (int n = 0; n < 4; ++n) {
            int col = ocol + n * 16;
            if (col < V_)
                __builtin_nontemporal_store(o, (f32x4*)(orp + col));
        }
    }
}

// ---------------------------------------------------------------------------
// Kernel 4: history scatter (unchanged)
// ---------------------------------------------------------------------------
__global__ __launch_bounds__(256) void hist_kernel(const int* __restrict__ loc,
                                                   const int* __restrict__ mask,
                                                   const float* __restrict__ rw,
                                                   const float* __restrict__ fw,
                                                   const float* __restrict__ hs,
                                                   float* __restrict__ out) {
    const int idx = blockIdx.x * 256 + threadIdx.x;
    if (idx >= B_ * L_) return;
    const int b = idx / L_, t = idx - b * L_;
    if (mask[idx] != 0) {
        float recency = expf(-0.1f * (float)(L_ - 1 - t)) * rw[0];
        float val = (recency + fw[0]) * hs[0];
        atomicAdd(out + (size_t)b * V_ + loc[idx], val);
    }
}

// ---------------------------------------------------------------------------
// DISCRIMINATOR ROUND: dur = 203.6 + T_noepi + 3*T_storeprobe
//   W-world ~560-630 | O-world ~380-430 | compute-slow ~450-520
// ---------------------------------------------------------------------------
extern "C" void kernel_launch(void* const* d_in, const int* in_sizes, int n_in,
                              void* d_out, int out_size, void* d_ws, size_t ws_size,
                              hipStream_t stream) {
    const float* hidden = (const float*)d_in[0];
    const int*   loc    = (const int*)d_in[1];
    const int*   mask   = (const int*)d_in[2];
    const float* W1     = (const float*)d_in[3];
    const float* b1     = (const float*)d_in[4];
    const float* gamma  = (const float*)d_in[5];
    const float* beta   = (const float*)d_in[6];
    const float* W2     = (const float*)d_in[7];
    const float* b2     = (const float*)d_in[8];
    const float* rw     = (const float*)d_in[9];
    const float* fw     = (const float*)d_in[10];
    const float* hs     = (const float*)d_in[11];
    const float* ls     = (const float*)d_in[12];
    float* out = (float*)d_out;

    __hip_bfloat16* WT   = (__hip_bfloat16*)d_ws;
    __hip_bfloat16* hbuf = (__hip_bfloat16*)((char*)d_ws + 20512768);

    const int NB = (B_ / BM) * (NPAD / BN);   // 5008

    transpose_w2<<<dim3(NPAD / 64, HID_ / 64), 256, 0, stream>>>(W2, WT);
    head_kernel<<<B_ / 8, 512, 0, stream>>>(hidden, W1, b1, gamma, beta, hbuf);

    gemm_kernel<0><<<NB, 256, 0, stream>>>(hbuf, WT, b2, ls, out);   // noepi x1
    for (int rep = 0; rep < 3; ++rep)
        store_probe<<<NB, 256, 0, stream>>>(ls, out);                // probe x3

    gemm_kernel<1><<<NB, 256, 0, stream>>>(hbuf, WT, b2, ls, out);   // real
    hist_kernel<<<(B_ * L_ + 255) / 256, 256, 0, stream>>>(loc, mask, rw, fw, hs, out);
}

// Round 9
// 209.292 us; speedup vs baseline: 2.8151x; 2.8151x over previous
//
#include <hip/hip_runtime.h>
#include <hip/hip_bf16.h>

#define B_   2048
#define L_   200
#define DM_  512
#define HID_ 256
#define V_   40000
#define NPAD 40064          // 313 * 128
#define LN_EPS 1e-5f

typedef short bf16x8 __attribute__((ext_vector_type(8)));
typedef float f32x4  __attribute__((ext_vector_type(4)));

#define GLOAD_LDS16(g, l)                                                     \
    __builtin_amdgcn_global_load_lds(                                         \
        (const __attribute__((address_space(1))) void*)(g),                   \
        (__attribute__((address_space(3))) void*)(l), 16, 0, 0)

#define BM 128
#define BN 128

// XCD-grouped block->tile mapping (R6)
__device__ inline void tile_map(int g, int& rt, int& ct) {
    const int G = g >> 7, ii = g & 127;
    if (G < 39) { ct = G * 8 + (ii & 7); rt = ii >> 3; }
    else        { ct = 312;              rt = ii & 15; }
}

// ---------------------------------------------------------------------------
// Kernel 1: W2 transpose+cvt (unchanged)
// ---------------------------------------------------------------------------
__global__ __launch_bounds__(256) void transpose_w2(const float* __restrict__ W2,
                                                    __hip_bfloat16* __restrict__ WT) {
    __shared__ float tile[64][65];
    const int n0 = blockIdx.x * 64;
    const int k0 = blockIdx.y * 64;
    const int tid = threadIdx.x;

    const int c = tid & 63, r4 = tid >> 6;
#pragma unroll
    for (int p = 0; p < 16; ++p) {
        int r = p * 4 + r4;
        int n = n0 + c;
        tile[r][c] = (n < V_) ? W2[(size_t)(k0 + r) * V_ + n] : 0.f;
    }
    __syncthreads();

    const int nl = tid >> 3;
    const int kb = (tid & 7) * 8;
#pragma unroll
    for (int p = 0; p < 2; ++p) {
        int n = p * 32 + nl;
        bf16x8 v;
#pragma unroll
        for (int j = 0; j < 8; ++j) {
            __hip_bfloat16 h = __float2bfloat16(tile[kb + j][n]);
            v[j] = *(short*)&h;
        }
        *(bf16x8*)(WT + (size_t)(n0 + n) * HID_ + k0 + kb) = v;
    }
}

// ---------------------------------------------------------------------------
// Kernel 2: head (unchanged)
// ---------------------------------------------------------------------------
__global__ __launch_bounds__(512) void head_kernel(const float* __restrict__ hidden,
                                                   const float* __restrict__ W1,
                                                   const float* __restrict__ b1,
                                                   const float* __restrict__ gamma,
                                                   const float* __restrict__ beta,
                                                   __hip_bfloat16* __restrict__ hout) {
    __shared__ float hid[8][DM_];
    __shared__ float part[8][HID_];
    __shared__ float red[2][8][4];
    const int r0 = blockIdx.x * 8;
    const int tid = threadIdx.x;
    const int col = tid & 255, half = tid >> 8;

    {
        const float4* src = (const float4*)(hidden + (size_t)r0 * DM_);
        float4* dst = (float4*)(&hid[0][0]);
        for (int i = tid; i < 8 * DM_ / 4; i += 512) dst[i] = src[i];
    }
    __syncthreads();

    float acc[8] = {0.f, 0.f, 0.f, 0.f, 0.f, 0.f, 0.f, 0.f};
    const int kbeg = half * (DM_ / 2);
#pragma unroll 8
    for (int k = kbeg; k < kbeg + DM_ / 2; ++k) {
        float w = W1[(size_t)k * HID_ + col];
#pragma unroll
        for (int r = 0; r < 8; ++r) acc[r] = fmaf(hid[r][k], w, acc[r]);
    }

    if (half == 1) {
#pragma unroll
        for (int r = 0; r < 8; ++r) part[r][col] = acc[r];
    }
    __syncthreads();
    if (half == 0) {
        const float b1v = b1[col], gv = gamma[col], bev = beta[col];
        const int lane = col & 63, wv = col >> 6;
        float v[8];
#pragma unroll
        for (int r = 0; r < 8; ++r) {
            v[r] = acc[r] + part[r][col] + b1v;
            float s = v[r], q = v[r] * v[r];
#pragma unroll
            for (int off = 1; off < 64; off <<= 1) {
                s += __shfl_xor(s, off);
                q += __shfl_xor(q, off);
            }
            if (lane == 0) { red[0][r][wv] = s; red[1][r][wv] = q; }
        }
        __syncthreads();
#pragma unroll
        for (int r = 0; r < 8; ++r) {
            float s  = red[0][r][0] + red[0][r][1] + red[0][r][2] + red[0][r][3];
            float q  = red[1][r][0] + red[1][r][1] + red[1][r][2] + red[1][r][3];
            float mu = s * (1.f / HID_);
            float var = q * (1.f / HID_) - mu * mu;
            float hn = (v[r] - mu) * rsqrtf(var + LN_EPS) * gv + bev;
            float g  = 0.5f * hn * (1.f + erff(hn * 0.70710678118654752f));
            hout[(size_t)(r0 + r) * HID_ + col] = __float2bfloat16(g);
        }
    }
}

// ---------------------------------------------------------------------------
// Kernel 3: GEMM — R6 body + LDS-restaged epilogue: every store instruction
// covers 2 full 512B row segments (full-line writes) instead of 16x64B.
// ---------------------------------------------------------------------------
__global__ __launch_bounds__(256, 1) void gemm_kernel(const __hip_bfloat16* __restrict__ hA,
                                                      const __hip_bfloat16* __restrict__ BT,
                                                      const float* __restrict__ b2,
                                                      const float* __restrict__ lsp,
                                                      float* __restrict__ out) {
    __shared__ __hip_bfloat16 As[BM * HID_];   // 64 KB (aliased by epilogue)
    __shared__ __hip_bfloat16 Bs[BN * HID_];   // 64 KB

    int rt, ct;
    tile_map(blockIdx.x, rt, ct);
    const int r0 = rt * BM, c0 = ct * BN;

    const int tid = threadIdx.x;
    const int lane = tid & 63;
    const int wv = tid >> 6;
    const int wr = (wv >> 1) * 64;
    const int wc = (wv & 1) * 64;
    const float ls = lsp[0];

    // stage ALL of K; LDS linear, source pre-swizzled (chunk c ^ (row&7))
    {
        const __hip_bfloat16* aB = hA + (size_t)r0 * HID_;
        const __hip_bfloat16* bB = BT + (size_t)c0 * HID_;
        const int cc = lane & 31;
        const int rhalf = lane >> 5;
#pragma unroll
        for (int i = 0; i < 16; ++i) {
            const int ch = wv * 16 + i;
            const int r = ch * 2 + rhalf;
            const int csrc = cc ^ (r & 7);
            GLOAD_LDS16(aB + (size_t)r * HID_ + csrc * 8, (char*)As + ch * 1024);
            GLOAD_LDS16(bB + (size_t)r * HID_ + csrc * 8, (char*)Bs + ch * 1024);
        }
    }
    __syncthreads();

    f32x4 acc[4][4];
#pragma unroll
    for (int m = 0; m < 4; ++m)
#pragma unroll
        for (int n = 0; n < 4; ++n) acc[m][n] = (f32x4){0.f, 0.f, 0.f, 0.f};

    const int rb = wr + (lane & 15);
    const int cb = wc + (lane & 15);
#pragma unroll
    for (int ks = 0; ks < HID_ / 32; ++ks) {
        const int kb = ks * 32 + ((lane >> 4) << 3);
        const int ke = kb ^ ((lane & 7) << 3);
        bf16x8 af[4], bf[4];
#pragma unroll
        for (int m = 0; m < 4; ++m)
            af[m] = *(const bf16x8*)(As + (size_t)(rb + m * 16) * HID_ + ke);
#pragma unroll
        for (int n = 0; n < 4; ++n)
            bf[n] = *(const bf16x8*)(Bs + (size_t)(cb + n * 16) * HID_ + ke);
#pragma unroll
        for (int m = 0; m < 4; ++m)
#pragma unroll
            for (int n = 0; n < 4; ++n)
                acc[m][n] = __builtin_amdgcn_mfma_f32_16x16x32_bf16(
                    bf[n], af[m], acc[m][n], 0, 0, 0);   // swapped -> C^T
    }

    // b2 + scale in acc domain (D^T layout: lane -> 4 consecutive cols)
    const int ocol = wc + ((lane >> 4) << 2);
    f32x4 b2v[4];
#pragma unroll
    for (int n = 0; n < 4; ++n) {
        int col = c0 + ocol + n * 16;
        b2v[n] = (col < V_) ? *(const f32x4*)(b2 + col)
                            : (f32x4){0.f, 0.f, 0.f, 0.f};
    }

    __syncthreads();                      // all MFMA LDS reads complete
    float* epi = (float*)As;              // 128x128 f32 = 64 KB alias

    // acc -> epi, XOR-swizzled 16B chunks (32 chunks per 512B row)
    {
        const int erow = wr + (lane & 15);
        const int ecol4 = (wc >> 2) + (lane >> 4);
#pragma unroll
        for (int m = 0; m < 4; ++m) {
            const int row = erow + m * 16;
#pragma unroll
            for (int n = 0; n < 4; ++n) {
                const int col4 = ecol4 + n * 4;
                const int swz = col4 ^ (row & 7);
                f32x4 o = (acc[m][n] + b2v[n]) * ls;
                *(f32x4*)((char*)epi + row * 512 + swz * 16) = o;
            }
        }
    }
    __syncthreads();

    // contiguous write-out: each wave instruction = 2 full 512B row segments
    {
        const int rr = tid >> 5;          // 0..7 (8 rows per iteration)
        const int chunk = tid & 31;       // 16B chunk within row
#pragma unroll
        for (int i = 0; i < 16; ++i) {
            const int row = i * 8 + rr;
            const int swz = chunk ^ (row & 7);
            f32x4 o = *(const f32x4*)((char*)epi + row * 512 + swz * 16);
            const int col = c0 + chunk * 4;
            if (col < V_)
                *(f32x4*)(out + (size_t)(r0 + row) * V_ + col) = o;
        }
    }
}

// ---------------------------------------------------------------------------
// Kernel 4: history scatter (unchanged)
// ---------------------------------------------------------------------------
__global__ __launch_bounds__(256) void hist_kernel(const int* __restrict__ loc,
                                                   const int* __restrict__ mask,
                                                   const float* __restrict__ rw,
                                                   const float* __restrict__ fw,
                                                   const float* __restrict__ hs,
                                                   float* __restrict__ out) {
    const int idx = blockIdx.x * 256 + threadIdx.x;
    if (idx >= B_ * L_) return;
    const int b = idx / L_, t = idx - b * L_;
    if (mask[idx] != 0) {
        float recency = expf(-0.1f * (float)(L_ - 1 - t)) * rw[0];
        float val = (recency + fw[0]) * hs[0];
        atomicAdd(out + (size_t)b * V_ + loc[idx], val);
    }
}

// ---------------------------------------------------------------------------
extern "C" void kernel_launch(void* const* d_in, const int* in_sizes, int n_in,
                              void* d_out, int out_size, void* d_ws, size_t ws_size,
                              hipStream_t stream) {
    const float* hidden = (const float*)d_in[0];
    const int*   loc    = (const int*)d_in[1];
    const int*   mask   = (const int*)d_in[2];
    const float* W1     = (const float*)d_in[3];
    const float* b1     = (const float*)d_in[4];
    const float* gamma  = (const float*)d_in[5];
    const float* beta   = (const float*)d_in[6];
    const float* W2     = (const float*)d_in[7];
    const float* b2     = (const float*)d_in[8];
    const float* rw     = (const float*)d_in[9];
    const float* fw     = (const float*)d_in[10];
    const float* hs     = (const float*)d_in[11];
    const float* ls     = (const float*)d_in[12];
    float* out = (float*)d_out;

    __hip_bfloat16* WT   = (__hip_bfloat16*)d_ws;
    __hip_bfloat16* hbuf = (__hip_bfloat16*)((char*)d_ws + 20512768);

    transpose_w2<<<dim3(NPAD / 64, HID_ / 64), 256, 0, stream>>>(W2, WT);
    head_kernel<<<B_ / 8, 512, 0, stream>>>(hidden, W1, b1, gamma, beta, hbuf);
    gemm_kernel<<<(B_ / BM) * (NPAD / BN), 256, 0, stream>>>(hbuf, WT, b2, ls, out);
    hist_kernel<<<(B_ * L_ + 255) / 256, 256, 0, stream>>>(loc, mask, rw, fw, hs, out);
}